// Round 10
// baseline (1666.165 us; speedup 1.0000x reference)
//
#include <hip/hip_runtime.h>
#include <math.h>

#define NROWS 262144

// Row layout (240 floats):
//   x0: [0,64)            (64 muls, l=0)
//   x1: [64,160)  u*3+i   (32 muls, l=1)
//   x2: [160,240) u*5+i   (16 muls, l=2)
// Output identical irrep layout: y0 [0,64), y1 [64,160) w*3+k, y2 [160,240) w*5+k
//
// Register-pressure design: every projection accumulation is chunked in w so
// that peak live VGPRs stay <= ~170 (3 waves/SIMD). All chunk loops are fully
// unrolled so output-array indices remain compile-time constants (runtime
// indexing of register arrays => scratch).

__global__ __launch_bounds__(256) void stp_kernel(
    const float* __restrict__ x,
    const float* __restrict__ w1_0, const float* __restrict__ w2_0,
    const float* __restrict__ w1_1, const float* __restrict__ w2_1,
    const float* __restrict__ w1_2, const float* __restrict__ w2_2,
    const float* __restrict__ w1_3, const float* __restrict__ w2_3,
    const float* __restrict__ w1_4, const float* __restrict__ w2_4,
    const float* __restrict__ w1_5, const float* __restrict__ w2_5,
    const float* __restrict__ w1_6, const float* __restrict__ w2_6,
    const float* __restrict__ w1_7, const float* __restrict__ w2_7,
    float* __restrict__ out)
{
    const int row = blockIdx.x * 256 + threadIdx.x;
    if (row >= NROWS) return;
    const float* __restrict__ xr = x + (size_t)row * 240;
    float* __restrict__ orow = out + (size_t)row * 240;

    // alpha = sqrt((2*l3+1)/tot[io]); tot = {5376, 2560, 2304}
    // diagonal w3j folded in: w3j(0,0,0)=1, (0,1,1)=(1,1,0)=I/sqrt3, (0,2,2)=(2,2,0)=I/sqrt5
    const float C0  = (float)(1.0/sqrt(5376.0));        // instr0
    const float C3  = (float)(1.0/sqrt(3.0*5376.0));    // instr3 (a3/sqrt3)
    const float C6  = (float)(1.0/sqrt(5.0*5376.0));    // instr6 (a6/sqrt5)
    const float C1  = (float)(1.0/sqrt(2560.0));        // instr1 (a1/sqrt3)
    const float C2  = (float)(1.0/48.0);                // instr2 (a2/sqrt5) = 1/sqrt(2304)
    const float A4  = (float)(sqrt(5.0/2304.0));
    const float A5  = (float)(sqrt(3.0/2560.0));
    const float A7  = (float)(sqrt(5.0/2304.0));
    // w3j(1,1,2) nonzeros (norm-1):  S10=1/sqrt10, S30=1/sqrt30, T215=sqrt(2/15)
    const float S10 = (float)(sqrt(1.0/10.0));
    const float S30 = (float)(sqrt(1.0/30.0));
    const float T215= (float)(sqrt(2.0/15.0));
    // w3j(2,2,2) nonzeros: D35=sqrt(2/35), E70=sqrt(3/70), F70=1/sqrt70
    const float D35 = (float)(sqrt(2.0/35.0));
    const float E70 = (float)(sqrt(3.0/70.0));
    const float F70 = (float)(sqrt(1.0/70.0));

    // ======================= Phase A : io=0  (y0[64]) =======================
    float y0[64];
    // instr0: (l0,l0)->l0, w in halves of 32
    #pragma unroll
    for (int h = 0; h < 2; ++h) {
        float t1[32], t2[32];
        #pragma unroll
        for (int w = 0; w < 32; ++w) { t1[w] = 0.f; t2[w] = 0.f; }
        #pragma unroll 2
        for (int u = 0; u < 64; ++u) {
            const float xv = xr[u];
            #pragma unroll
            for (int w = 0; w < 32; ++w) {
                t1[w] = fmaf(xv, w1_0[u*64 + h*32 + w], t1[w]);
                t2[w] = fmaf(xv, w2_0[u*64 + h*32 + w], t2[w]);
            }
        }
        #pragma unroll
        for (int w = 0; w < 32; ++w) y0[h*32+w] = C0 * t1[w] * t2[w];
    }
    // instr3: (l1,l1)->l0, diagonal in component i; w in halves of 32
    #pragma unroll 1
    for (int i = 0; i < 3; ++i) {
        #pragma unroll
        for (int h = 0; h < 2; ++h) {
            float t1[32], t2[32];
            #pragma unroll
            for (int w = 0; w < 32; ++w) { t1[w] = 0.f; t2[w] = 0.f; }
            #pragma unroll 2
            for (int u = 0; u < 32; ++u) {
                const float xv = xr[64 + u*3 + i];
                #pragma unroll
                for (int w = 0; w < 32; ++w) {
                    t1[w] = fmaf(xv, w1_3[u*64 + h*32 + w], t1[w]);
                    t2[w] = fmaf(xv, w2_3[u*64 + h*32 + w], t2[w]);
                }
            }
            #pragma unroll
            for (int w = 0; w < 32; ++w) y0[h*32+w] = fmaf(C3 * t1[w], t2[w], y0[h*32+w]);
        }
    }
    // instr6: (l2,l2)->l0, diagonal in component i; w in halves of 32
    #pragma unroll 1
    for (int i = 0; i < 5; ++i) {
        #pragma unroll
        for (int h = 0; h < 2; ++h) {
            float t1[32], t2[32];
            #pragma unroll
            for (int w = 0; w < 32; ++w) { t1[w] = 0.f; t2[w] = 0.f; }
            #pragma unroll 2
            for (int u = 0; u < 16; ++u) {
                const float xv = xr[160 + u*5 + i];
                #pragma unroll
                for (int w = 0; w < 32; ++w) {
                    t1[w] = fmaf(xv, w1_6[u*64 + h*32 + w], t1[w]);
                    t2[w] = fmaf(xv, w2_6[u*64 + h*32 + w], t2[w]);
                }
            }
            #pragma unroll
            for (int w = 0; w < 32; ++w) y0[h*32+w] = fmaf(C6 * t1[w], t2[w], y0[h*32+w]);
        }
    }
    #pragma unroll
    for (int q = 0; q < 16; ++q)
        *reinterpret_cast<float4*>(orow + 4*q) =
            make_float4(y0[4*q+0], y0[4*q+1], y0[4*q+2], y0[4*q+3]);

    // ======================= Phase B : io=1  (y1[96]) =======================
    float y1[96];
    // instr1: (l0,l1)->l1 : y1[w,k] = C1 * t1[w] * t2[w,k]; w in halves of 16
    #pragma unroll
    for (int h = 0; h < 2; ++h) {
        float t1w[16];
        #pragma unroll
        for (int w = 0; w < 16; ++w) t1w[w] = 0.f;
        #pragma unroll 2
        for (int u = 0; u < 64; ++u) {
            const float xv = xr[u];
            #pragma unroll
            for (int w = 0; w < 16; ++w) t1w[w] = fmaf(xv, w1_1[u*32 + h*16 + w], t1w[w]);
        }
        #pragma unroll
        for (int k = 0; k < 3; ++k) {
            float t2[16];
            #pragma unroll
            for (int w = 0; w < 16; ++w) t2[w] = 0.f;
            #pragma unroll 2
            for (int u = 0; u < 32; ++u) {
                const float xv = xr[64 + u*3 + k];
                #pragma unroll
                for (int w = 0; w < 16; ++w) t2[w] = fmaf(xv, w2_1[u*32 + h*16 + w], t2[w]);
            }
            #pragma unroll
            for (int w = 0; w < 16; ++w) y1[(h*16+w)*3+k] = C1 * t1w[w] * t2[w];
        }
    }
    // instr5: (l1,l2)->l1 via w3j(1,2,1)[i,j,k] = w3j(1,1,2)[i,k,j]; w in chunks of 8
    #pragma unroll
    for (int wc = 0; wc < 4; ++wc) {
        float p[24], q[40];
        #pragma unroll
        for (int t = 0; t < 24; ++t) p[t] = 0.f;
        #pragma unroll
        for (int t = 0; t < 40; ++t) q[t] = 0.f;
        #pragma unroll 2
        for (int u = 0; u < 32; ++u) {
            #pragma unroll
            for (int i = 0; i < 3; ++i) {
                const float xv = xr[64 + u*3 + i];
                #pragma unroll
                for (int w = 0; w < 8; ++w)
                    p[w*3+i] = fmaf(xv, w1_5[u*32 + wc*8 + w], p[w*3+i]);
            }
        }
        #pragma unroll 2
        for (int u = 0; u < 16; ++u) {
            #pragma unroll
            for (int j = 0; j < 5; ++j) {
                const float xv = xr[160 + u*5 + j];
                #pragma unroll
                for (int w = 0; w < 8; ++w)
                    q[w*5+j] = fmaf(xv, w2_5[u*32 + wc*8 + w], q[w*5+j]);
            }
        }
        #pragma unroll
        for (int w = 0; w < 8; ++w) {
            const int wg = wc*8 + w;
            const float p0=p[w*3+0], p1=p[w*3+1], p2=p[w*3+2];
            const float q0=q[w*5+0], q1=q[w*5+1], q2=q[w*5+2], q3=q[w*5+3], q4=q[w*5+4];
            y1[wg*3+0] += A5*( S10*(p1*q1 + p2*q0 - p0*q4) - S30*(p0*q2) );
            y1[wg*3+1] += A5*( S10*(p0*q1 + p2*q3) + T215*(p1*q2) );
            y1[wg*3+2] += A5*( S10*(p0*q0 + p1*q3 + p2*q4) - S30*(p2*q2) );
        }
    }
    #pragma unroll
    for (int q4 = 0; q4 < 24; ++q4)
        *reinterpret_cast<float4*>(orow + 64 + 4*q4) =
            make_float4(y1[4*q4+0], y1[4*q4+1], y1[4*q4+2], y1[4*q4+3]);

    // ======================= Phase C : io=2  (y2[80]) =======================
    float y2[80];
    {   // instr2: (l0,l2)->l2 : y2[w,k] = C2 * t1w[w] * t2[w,k]
        float t1w[16];
        #pragma unroll
        for (int w = 0; w < 16; ++w) t1w[w] = 0.f;
        #pragma unroll 2
        for (int u = 0; u < 64; ++u) {
            const float xv = xr[u];
            #pragma unroll
            for (int w = 0; w < 16; ++w) t1w[w] = fmaf(xv, w1_2[u*16+w], t1w[w]);
        }
        #pragma unroll
        for (int k = 0; k < 5; ++k) {
            float t2[16];
            #pragma unroll
            for (int w = 0; w < 16; ++w) t2[w] = 0.f;
            #pragma unroll 2
            for (int u = 0; u < 16; ++u) {
                const float xv = xr[160 + u*5 + k];
                #pragma unroll
                for (int w = 0; w < 16; ++w) t2[w] = fmaf(xv, w2_2[u*16+w], t2[w]);
            }
            #pragma unroll
            for (int w = 0; w < 16; ++w) y2[w*5+k] = C2 * t1w[w] * t2[w];
        }
    }
    // instr4: (l1,l1)->l2 via w3j(1,1,2); w in chunks of 8
    #pragma unroll
    for (int wc = 0; wc < 2; ++wc) {
        float p[24], q[24];
        #pragma unroll
        for (int t = 0; t < 24; ++t) { p[t] = 0.f; q[t] = 0.f; }
        #pragma unroll 2
        for (int u = 0; u < 32; ++u) {
            #pragma unroll
            for (int i = 0; i < 3; ++i) {
                const float xv = xr[64 + u*3 + i];
                #pragma unroll
                for (int w = 0; w < 8; ++w) {
                    p[w*3+i] = fmaf(xv, w1_4[u*16 + wc*8 + w], p[w*3+i]);
                    q[w*3+i] = fmaf(xv, w2_4[u*16 + wc*8 + w], q[w*3+i]);
                }
            }
        }
        #pragma unroll
        for (int w = 0; w < 8; ++w) {
            const int wg = wc*8 + w;
            const float p0=p[w*3+0], p1=p[w*3+1], p2=p[w*3+2];
            const float q0=q[w*3+0], q1=q[w*3+1], q2=q[w*3+2];
            y2[wg*5+0] += A4*S10*(p0*q2 + p2*q0);
            y2[wg*5+1] += A4*S10*(p0*q1 + p1*q0);
            y2[wg*5+2] += A4*( T215*(p1*q1) - S30*(p0*q0 + p2*q2) );
            y2[wg*5+3] += A4*S10*(p1*q2 + p2*q1);
            y2[wg*5+4] += A4*S10*(p2*q2 - p0*q0);
        }
    }
    // instr7: (l2,l2)->l2 via w3j(2,2,2); w in chunks of 8
    #pragma unroll
    for (int wc = 0; wc < 2; ++wc) {
        float p[40], q[40];
        #pragma unroll
        for (int t = 0; t < 40; ++t) { p[t] = 0.f; q[t] = 0.f; }
        #pragma unroll 2
        for (int u = 0; u < 16; ++u) {
            #pragma unroll
            for (int j = 0; j < 5; ++j) {
                const float xv = xr[160 + u*5 + j];
                #pragma unroll
                for (int w = 0; w < 8; ++w) {
                    p[w*5+j] = fmaf(xv, w1_7[u*16 + wc*8 + w], p[w*5+j]);
                    q[w*5+j] = fmaf(xv, w2_7[u*16 + wc*8 + w], q[w*5+j]);
                }
            }
        }
        #pragma unroll
        for (int w = 0; w < 8; ++w) {
            const int wg = wc*8 + w;
            const float p0=p[w*5+0], p1=p[w*5+1], p2=p[w*5+2], p3=p[w*5+3], p4=p[w*5+4];
            const float q0=q[w*5+0], q1=q[w*5+1], q2=q[w*5+2], q3=q[w*5+3], q4=q[w*5+4];
            y2[wg*5+0] += A7*( -D35*(p0*q2 + p2*q0) + E70*(p1*q3 + p3*q1) );
            y2[wg*5+1] += A7*(  E70*(p0*q3 + p3*q0 - p4*q1 - p1*q4) + F70*(p1*q2 + p2*q1) );
            y2[wg*5+2] += A7*(  D35*(p2*q2 - p0*q0 - p4*q4) + F70*(p1*q1 + p3*q3) );
            y2[wg*5+3] += A7*(  E70*(p0*q1 + p1*q0 + p4*q3 + p3*q4) + F70*(p3*q2 + p2*q3) );
            y2[wg*5+4] += A7*( -D35*(p4*q2 + p2*q4) + E70*(p3*q3 - p1*q1) );
        }
    }
    #pragma unroll
    for (int q4 = 0; q4 < 20; ++q4)
        *reinterpret_cast<float4*>(orow + 160 + 4*q4) =
            make_float4(y2[4*q4+0], y2[4*q4+1], y2[4*q4+2], y2[4*q4+3]);
}

extern "C" void kernel_launch(void* const* d_in, const int* in_sizes, int n_in,
                              void* d_out, int out_size, void* d_ws, size_t ws_size,
                              hipStream_t stream)
{
    const float* x = (const float*)d_in[0];
    const float* w[16];
    for (int i = 0; i < 16; ++i) w[i] = (const float*)d_in[1 + i];
    float* outp = (float*)d_out;

    dim3 grid(NROWS / 256), block(256);
    hipLaunchKernelGGL(stp_kernel, grid, block, 0, stream,
                       x,
                       w[0],  w[1],  w[2],  w[3],
                       w[4],  w[5],  w[6],  w[7],
                       w[8],  w[9],  w[10], w[11],
                       w[12], w[13], w[14], w[15],
                       outp);
}

// Round 11
// 1138.690 us; speedup vs baseline: 1.4632x; 1.4632x over previous
//
#include <hip/hip_runtime.h>
#include <math.h>

#define NROWS 262144
#define RPB   64      // rows per block (lane = row)
#define TPB   512     // 8 waves; wave q owns a w-slice
// LDS strides (padded): x0 LEN=64 S=65, x1 LEN=96 S=97, x2 LEN=80 S=81
#define LDS_FLOATS 6208   // 64*97

template<int OFF, int LEN, int S>
__device__ __forceinline__ void stage_seg(const float* __restrict__ x,
                                          float* __restrict__ lds,
                                          int row0, int tid)
{
    constexpr int NV = RPB * LEN / 4;            // float4 elements
    constexpr int IT = (NV + TPB - 1) / TPB;
    #pragma unroll
    for (int it = 0; it < IT; ++it) {
        int idx = it * TPB + tid;
        if (NV % TPB != 0) { if (idx >= NV) break; }
        int rw = idx / (LEN / 4);
        int c4 = idx % (LEN / 4);
        const float4 v = *reinterpret_cast<const float4*>(
            x + (size_t)(row0 + rw) * 240 + OFF + c4 * 4);
        float* d = lds + rw * S + c4 * 4;
        d[0] = v.x; d[1] = v.y; d[2] = v.z; d[3] = v.w;
    }
}

__global__ __launch_bounds__(512) void stp_kernel(
    const float* __restrict__ x,
    const float* __restrict__ w1_0, const float* __restrict__ w2_0,
    const float* __restrict__ w1_1, const float* __restrict__ w2_1,
    const float* __restrict__ w1_2, const float* __restrict__ w2_2,
    const float* __restrict__ w1_3, const float* __restrict__ w2_3,
    const float* __restrict__ w1_4, const float* __restrict__ w2_4,
    const float* __restrict__ w1_5, const float* __restrict__ w2_5,
    const float* __restrict__ w1_6, const float* __restrict__ w2_6,
    const float* __restrict__ w1_7, const float* __restrict__ w2_7,
    float* __restrict__ out)
{
    __shared__ float lds[LDS_FLOATS];

    const int tid = threadIdx.x;
    // wave id (wave-uniform by construction; readfirstlane pins it to an SGPR
    // so all weight addressing becomes scalar -> s_load through K$)
    const int q = __builtin_amdgcn_readfirstlane(tid >> 6);
    const int r = tid & 63;                        // lane = row in tile
    const int row0 = blockIdx.x * RPB;

    const int q8 = q * 8, q4 = q * 4, q2 = q * 2;  // w-slice bases

    // constants (same derivation as validated round-10 kernel)
    const float C0  = (float)(1.0/sqrt(5376.0));
    const float C3  = (float)(1.0/sqrt(3.0*5376.0));
    const float C6  = (float)(1.0/sqrt(5.0*5376.0));
    const float C1c = (float)(1.0/sqrt(2560.0));
    const float C2c = (float)(1.0/48.0);
    const float A4  = (float)(sqrt(5.0/2304.0));
    const float A5  = (float)(sqrt(3.0/2560.0));
    const float A7  = (float)(sqrt(5.0/2304.0));
    const float S10 = (float)(sqrt(1.0/10.0));
    const float S30 = (float)(sqrt(1.0/30.0));
    const float T215= (float)(sqrt(2.0/15.0));
    const float D35 = (float)(sqrt(2.0/35.0));
    const float E70 = (float)(sqrt(3.0/70.0));
    const float F70 = (float)(sqrt(1.0/70.0));

    // =============== SEG A : x0 (cols 0..63, stride 65) ===============
    stage_seg<0, 64, 65>(x, lds, row0, tid);
    __syncthreads();

    float y0[8];                 // instr0/3/6 accumulator (w = q8+0..7)
    float B1[4];                 // instr1 t1w (w = q4+0..3)
    float Cw[2];                 // instr2 t1w (w = q2+0..1)
    {
        float t1[8], t2[8];
        #pragma unroll
        for (int w = 0; w < 8; ++w) { t1[w] = 0.f; t2[w] = 0.f; }
        #pragma unroll
        for (int w = 0; w < 4; ++w) B1[w] = 0.f;
        Cw[0] = 0.f; Cw[1] = 0.f;
        #pragma unroll 4
        for (int u = 0; u < 64; ++u) {
            const float xv = lds[r * 65 + u];
            #pragma unroll
            for (int w = 0; w < 8; ++w) {
                t1[w] = fmaf(xv, w1_0[u*64 + q8 + w], t1[w]);
                t2[w] = fmaf(xv, w2_0[u*64 + q8 + w], t2[w]);
            }
            #pragma unroll
            for (int w = 0; w < 4; ++w) B1[w] = fmaf(xv, w1_1[u*32 + q4 + w], B1[w]);
            #pragma unroll
            for (int w = 0; w < 2; ++w) Cw[w] = fmaf(xv, w1_2[u*16 + q2 + w], Cw[w]);
        }
        #pragma unroll
        for (int w = 0; w < 8; ++w) y0[w] = C0 * t1[w] * t2[w];
    }
    __syncthreads();   // LDS about to be overwritten

    // =============== SEG B : x1 (cols 64..159, stride 97) ===============
    stage_seg<64, 96, 97>(x, lds, row0, tid);
    __syncthreads();

    float y1[12];                // (wl*3+k), w = q4+wl
    float y2[10];                // (wl*5+k), w = q2+wl
    float p5[12];                // instr5 p (wl*3+i)
    float p4a[6], q4a[6];        // instr4 p,q (wl*3+i)
    #pragma unroll
    for (int t = 0; t < 12; ++t) p5[t] = 0.f;
    #pragma unroll
    for (int t = 0; t < 6; ++t) { p4a[t] = 0.f; q4a[t] = 0.f; }

    #pragma unroll
    for (int i = 0; i < 3; ++i) {
        float t1[8], t2[8], t2b[4];
        #pragma unroll
        for (int w = 0; w < 8; ++w) { t1[w] = 0.f; t2[w] = 0.f; }
        #pragma unroll
        for (int w = 0; w < 4; ++w) t2b[w] = 0.f;
        #pragma unroll 4
        for (int u = 0; u < 32; ++u) {
            const float xv = lds[r * 97 + u*3 + i];
            #pragma unroll
            for (int w = 0; w < 8; ++w) {
                t1[w] = fmaf(xv, w1_3[u*64 + q8 + w], t1[w]);
                t2[w] = fmaf(xv, w2_3[u*64 + q8 + w], t2[w]);
            }
            #pragma unroll
            for (int w = 0; w < 4; ++w) {
                t2b[w]      = fmaf(xv, w2_1[u*32 + q4 + w], t2b[w]);
                p5[w*3 + i] = fmaf(xv, w1_5[u*32 + q4 + w], p5[w*3 + i]);
            }
            #pragma unroll
            for (int w = 0; w < 2; ++w) {
                p4a[w*3 + i] = fmaf(xv, w1_4[u*16 + q2 + w], p4a[w*3 + i]);
                q4a[w*3 + i] = fmaf(xv, w2_4[u*16 + q2 + w], q4a[w*3 + i]);
            }
        }
        #pragma unroll
        for (int w = 0; w < 8; ++w) y0[w] = fmaf(C3 * t1[w], t2[w], y0[w]);
        #pragma unroll
        for (int w = 0; w < 4; ++w) y1[w*3 + i] = C1c * B1[w] * t2b[w];
    }
    // instr4 -> initialize y2
    #pragma unroll
    for (int w = 0; w < 2; ++w) {
        const float p0 = p4a[w*3+0], p1 = p4a[w*3+1], p2 = p4a[w*3+2];
        const float q0 = q4a[w*3+0], q1 = q4a[w*3+1], q2 = q4a[w*3+2];
        y2[w*5+0] = A4*S10*(p0*q2 + p2*q0);
        y2[w*5+1] = A4*S10*(p0*q1 + p1*q0);
        y2[w*5+2] = A4*( T215*(p1*q1) - S30*(p0*q0 + p2*q2) );
        y2[w*5+3] = A4*S10*(p1*q2 + p2*q1);
        y2[w*5+4] = A4*S10*(p2*q2 - p0*q0);
    }
    __syncthreads();

    // =============== SEG C : x2 (cols 160..239, stride 81) ===============
    stage_seg<160, 80, 81>(x, lds, row0, tid);
    __syncthreads();

    float q5a[20];   // instr5 q (wl*5+j), w = q4+wl
    float p7[10], q7[10];   // instr7 (wl*5+j), w = q2+wl
    #pragma unroll
    for (int t = 0; t < 20; ++t) q5a[t] = 0.f;
    #pragma unroll
    for (int t = 0; t < 10; ++t) { p7[t] = 0.f; q7[t] = 0.f; }

    #pragma unroll
    for (int j = 0; j < 5; ++j) {
        float t1[8], t2[8], t2c[2];
        #pragma unroll
        for (int w = 0; w < 8; ++w) { t1[w] = 0.f; t2[w] = 0.f; }
        t2c[0] = 0.f; t2c[1] = 0.f;
        #pragma unroll 4
        for (int u = 0; u < 16; ++u) {
            const float xv = lds[r * 81 + u*5 + j];
            #pragma unroll
            for (int w = 0; w < 8; ++w) {
                t1[w] = fmaf(xv, w1_6[u*64 + q8 + w], t1[w]);
                t2[w] = fmaf(xv, w2_6[u*64 + q8 + w], t2[w]);
            }
            #pragma unroll
            for (int w = 0; w < 4; ++w)
                q5a[w*5 + j] = fmaf(xv, w2_5[u*32 + q4 + w], q5a[w*5 + j]);
            #pragma unroll
            for (int w = 0; w < 2; ++w) {
                t2c[w]       = fmaf(xv, w2_2[u*16 + q2 + w], t2c[w]);
                p7[w*5 + j]  = fmaf(xv, w1_7[u*16 + q2 + w], p7[w*5 + j]);
                q7[w*5 + j]  = fmaf(xv, w2_7[u*16 + q2 + w], q7[w*5 + j]);
            }
        }
        #pragma unroll
        for (int w = 0; w < 8; ++w) y0[w] = fmaf(C6 * t1[w], t2[w], y0[w]);
        #pragma unroll
        for (int w = 0; w < 2; ++w)
            y2[w*5 + j] = fmaf(C2c * Cw[w], t2c[w], y2[w*5 + j]);
    }

    float* __restrict__ orow = out + (size_t)(row0 + r) * 240;

    // write y0 (w = q8..q8+7): 2x float4, 16B-aligned
    {
        float4* o = reinterpret_cast<float4*>(orow + q8);
        o[0] = make_float4(y0[0], y0[1], y0[2], y0[3]);
        o[1] = make_float4(y0[4], y0[5], y0[6], y0[7]);
    }

    // instr5 combine into y1
    #pragma unroll
    for (int w = 0; w < 4; ++w) {
        const float p0 = p5[w*3+0], p1 = p5[w*3+1], p2 = p5[w*3+2];
        const float q0 = q5a[w*5+0], q1 = q5a[w*5+1], q2 = q5a[w*5+2],
                    q3 = q5a[w*5+3], q4v = q5a[w*5+4];
        y1[w*3+0] += A5*( S10*(p1*q1 + p2*q0 - p0*q4v) - S30*(p0*q2) );
        y1[w*3+1] += A5*( S10*(p0*q1 + p2*q3) + T215*(p1*q2) );
        y1[w*3+2] += A5*( S10*(p0*q0 + p1*q3 + p2*q4v) - S30*(p2*q2) );
    }
    // write y1 (cols 64 + q*12 .. +11): 3x float4, 16B-aligned
    {
        float4* o = reinterpret_cast<float4*>(orow + 64 + q * 12);
        o[0] = make_float4(y1[0], y1[1], y1[2],  y1[3]);
        o[1] = make_float4(y1[4], y1[5], y1[6],  y1[7]);
        o[2] = make_float4(y1[8], y1[9], y1[10], y1[11]);
    }

    // instr7 combine into y2
    #pragma unroll
    for (int w = 0; w < 2; ++w) {
        const float p0 = p7[w*5+0], p1 = p7[w*5+1], p2 = p7[w*5+2],
                    p3 = p7[w*5+3], p4v = p7[w*5+4];
        const float q0 = q7[w*5+0], q1 = q7[w*5+1], q2 = q7[w*5+2],
                    q3 = q7[w*5+3], q4v = q7[w*5+4];
        y2[w*5+0] += A7*( -D35*(p0*q2 + p2*q0) + E70*(p1*q3 + p3*q1) );
        y2[w*5+1] += A7*(  E70*(p0*q3 + p3*q0 - p4v*q1 - p1*q4v) + F70*(p1*q2 + p2*q1) );
        y2[w*5+2] += A7*(  D35*(p2*q2 - p0*q0 - p4v*q4v) + F70*(p1*q1 + p3*q3) );
        y2[w*5+3] += A7*(  E70*(p0*q1 + p1*q0 + p4v*q3 + p3*q4v) + F70*(p3*q2 + p2*q3) );
        y2[w*5+4] += A7*( -D35*(p4v*q2 + p2*q4v) + E70*(p3*q3 - p1*q1) );
    }
    // write y2 (cols 160 + q*10 .. +9): 5x float2 (8B-aligned; 16B not guaranteed for odd q)
    {
        float2* o = reinterpret_cast<float2*>(orow + 160 + q * 10);
        o[0] = make_float2(y2[0], y2[1]);
        o[1] = make_float2(y2[2], y2[3]);
        o[2] = make_float2(y2[4], y2[5]);
        o[3] = make_float2(y2[6], y2[7]);
        o[4] = make_float2(y2[8], y2[9]);
    }
}

extern "C" void kernel_launch(void* const* d_in, const int* in_sizes, int n_in,
                              void* d_out, int out_size, void* d_ws, size_t ws_size,
                              hipStream_t stream)
{
    const float* x = (const float*)d_in[0];
    const float* w[16];
    for (int i = 0; i < 16; ++i) w[i] = (const float*)d_in[1 + i];
    float* outp = (float*)d_out;

    dim3 grid(NROWS / RPB), block(TPB);
    hipLaunchKernelGGL(stp_kernel, grid, block, 0, stream,
                       x,
                       w[0],  w[1],  w[2],  w[3],
                       w[4],  w[5],  w[6],  w[7],
                       w[8],  w[9],  w[10], w[11],
                       w[12], w[13], w[14], w[15],
                       outp);
}

// Round 13
// 802.807 us; speedup vs baseline: 2.0754x; 1.4184x over previous
//
#include <hip/hip_runtime.h>
#include <math.h>

#define NROWS 262144
#define RPB   64
#define TPB   256

typedef __attribute__((ext_vector_type(8))) short short8v;   // 8 bf16 = 4 VGPR
typedef __attribute__((ext_vector_type(4))) float f32x4;

#define MFMA16 __builtin_amdgcn_mfma_f32_16x16x32_bf16

// f32 -> bf16 round-to-nearest-even
__device__ __forceinline__ unsigned short f2bf(float f){
    unsigned u = __float_as_uint(f);
    unsigned r = (u + 0x7FFFu + ((u >> 16) & 1u)) >> 16;
    return (unsigned short)r;
}

// ---- pre-fragmented weight buffer layout (elements of bf16) ----
// Full frag (K>=32): 512 el, lane l (0..63) holds B[kt*32+(l>>4)*8+h][nt*16+(l&15)], h=0..7
// Half frag (K==16): 256 el, lanes 0..31 only.
// slot offsets:
//  W10@0 W20@4096 W11@8192 W12@10240 W13@11264 W23@13312 W21@15360 W15@16384
//  W14@17408 W24@17920 W16@18432 W26@19456 W25@20480 W22@20992 W17@21248 W27@21504  total 21760

__global__ __launch_bounds__(256) void wprep_kernel(
    const float* __restrict__ W10, const float* __restrict__ W20,
    const float* __restrict__ W11, const float* __restrict__ W12,
    const float* __restrict__ W13, const float* __restrict__ W23,
    const float* __restrict__ W21, const float* __restrict__ W15,
    const float* __restrict__ W14, const float* __restrict__ W24,
    const float* __restrict__ W16, const float* __restrict__ W26,
    const float* __restrict__ W25, const float* __restrict__ W22,
    const float* __restrict__ W17, const float* __restrict__ W27,
    unsigned short* __restrict__ ws)
{
    int e = blockIdx.x * 256 + threadIdx.x;
    if (e >= 21760) return;
    const float* wp; int K, N, base;
    if      (e < 4096)  { wp=W10; K=64; N=64; base=0; }
    else if (e < 8192)  { wp=W20; K=64; N=64; base=4096; }
    else if (e < 10240) { wp=W11; K=64; N=32; base=8192; }
    else if (e < 11264) { wp=W12; K=64; N=16; base=10240; }
    else if (e < 13312) { wp=W13; K=32; N=64; base=11264; }
    else if (e < 15360) { wp=W23; K=32; N=64; base=13312; }
    else if (e < 16384) { wp=W21; K=32; N=32; base=15360; }
    else if (e < 17408) { wp=W15; K=32; N=32; base=16384; }
    else if (e < 17920) { wp=W14; K=32; N=16; base=17408; }
    else if (e < 18432) { wp=W24; K=32; N=16; base=17920; }
    else if (e < 19456) { wp=W16; K=16; N=64; base=18432; }
    else if (e < 20480) { wp=W26; K=16; N=64; base=19456; }
    else if (e < 20992) { wp=W25; K=16; N=32; base=20480; }
    else if (e < 21248) { wp=W22; K=16; N=16; base=20992; }
    else if (e < 21504) { wp=W17; K=16; N=16; base=21248; }
    else                { wp=W27; K=16; N=16; base=21504; }
    int el = e - base, k, n;
    if (K == 16) {
        int nt = el >> 8; int lane = (el >> 3) & 31; int h = el & 7;
        k = ((lane >> 4) << 3) + h;
        n = (nt << 4) + (lane & 15);
    } else {
        int frag = el >> 9; int lane = (el >> 3) & 63; int h = el & 7;
        int kt, nt;
        if (K == 64) { kt = frag & 1; nt = frag >> 1; } else { kt = 0; nt = frag; }
        k = kt*32 + ((lane >> 4) << 3) + h;
        n = nt*16 + (lane & 15);
    }
    ws[e] = f2bf(wp[k * N + n]);
}

__global__ __launch_bounds__(256, 2) void stp_mfma(
    const float* __restrict__ x,
    const unsigned short* __restrict__ ws,
    float* __restrict__ out)
{
    __shared__ short wfrag[21760];              // 43520 B
    __shared__ short xbuf[7680];                // 15360 B (x0:64x72 | x1d:3x64x40 | x2d:5x64x24)

    const int tid = threadIdx.x;
    const int l   = tid & 63;
    const int wv  = tid >> 6;                   // wave = row-tile 0..3
    const int rr  = l & 15;
    const int kq  = l >> 4;
    const int row0 = blockIdx.x * RPB;

    const float C0  = (float)(1.0/sqrt(5376.0));
    const float C3  = (float)(1.0/sqrt(3.0*5376.0));
    const float C6  = (float)(1.0/sqrt(5.0*5376.0));
    const float C1c = (float)(1.0/sqrt(2560.0));
    const float C2c = (float)(1.0/48.0);
    const float A4  = (float)(sqrt(5.0/2304.0));
    const float A5  = (float)(sqrt(3.0/2560.0));
    const float A7  = (float)(sqrt(5.0/2304.0));
    const float S10 = (float)(sqrt(1.0/10.0));
    const float S30 = (float)(sqrt(1.0/30.0));
    const float T215= (float)(sqrt(2.0/15.0));
    const float D35 = (float)(sqrt(2.0/35.0));
    const float E70 = (float)(sqrt(3.0/70.0));
    const float F70 = (float)(sqrt(1.0/70.0));
    const float A5S10 = A5*S10, A5S30 = A5*S30, A5T = A5*T215;

    const f32x4 zf = {0.f, 0.f, 0.f, 0.f};
    const short8v z8 = {0,0,0,0,0,0,0,0};

#define LDW(off)  (*reinterpret_cast<const short8v*>(&wfrag[(off) + l*8]))
#define LDWH(off) ((l < 32) ? (*reinterpret_cast<const short8v*>(&wfrag[(off) + l*8])) : z8)

    // ---------------- phase 0: weights ws->LDS, stage x0 ----------------
    #pragma unroll
    for (int it = 0; it < 11; ++it) {
        int fi = it*256 + tid;
        if (fi < 2720) {
            short8v v = *reinterpret_cast<const short8v*>(ws + fi*8);
            *reinterpret_cast<short8v*>(&wfrag[fi*8]) = v;
        }
    }
    #pragma unroll
    for (int it = 0; it < 4; ++it) {            // 1024 float4 = 64 rows x 16
        int fi = it*256 + tid;
        int row = fi >> 4, c4 = fi & 15;
        float4 v = *reinterpret_cast<const float4*>(x + (size_t)(row0+row)*240 + c4*4);
        unsigned long long pk = (unsigned long long)f2bf(v.x)
                              | ((unsigned long long)f2bf(v.y) << 16)
                              | ((unsigned long long)f2bf(v.z) << 32)
                              | ((unsigned long long)f2bf(v.w) << 48);
        *reinterpret_cast<unsigned long long*>(&xbuf[row*72 + c4*4]) = pk;
    }
    __syncthreads();

    // ---------------- phase A: x0 GEMMs (K=64) ----------------
    f32x4 y0[4], t1w[2], Cw;
    {
        const int rl = wv*16 + rr;
        short8v a0 = *reinterpret_cast<const short8v*>(&xbuf[rl*72 +      kq*8]);
        short8v a1 = *reinterpret_cast<const short8v*>(&xbuf[rl*72 + 32 + kq*8]);
        #pragma unroll
        for (int nt = 0; nt < 4; ++nt) {
            f32x4 t1 = MFMA16(a0, LDW(0     + (nt*2+0)*512), zf, 0,0,0);
            t1       = MFMA16(a1, LDW(0     + (nt*2+1)*512), t1, 0,0,0);
            f32x4 t2 = MFMA16(a0, LDW(4096  + (nt*2+0)*512), zf, 0,0,0);
            t2       = MFMA16(a1, LDW(4096  + (nt*2+1)*512), t2, 0,0,0);
            y0[nt] = C0 * (t1 * t2);
        }
        #pragma unroll
        for (int nt = 0; nt < 2; ++nt) {
            f32x4 t = MFMA16(a0, LDW(8192 + (nt*2+0)*512), zf, 0,0,0);
            t       = MFMA16(a1, LDW(8192 + (nt*2+1)*512), t,  0,0,0);
            t1w[nt] = t;
        }
        {
            f32x4 t = MFMA16(a0, LDW(10240      ), zf, 0,0,0);
            Cw      = MFMA16(a1, LDW(10240 + 512), t,  0,0,0);
        }
    }
    __syncthreads();

    // stage x1d (de-interleaved per component i): xbuf[i*2560 + row*40 + u]
    #pragma unroll
    for (int it = 0; it < 6; ++it) {            // 1536 float4 = 64 rows x 24
        int fi = it*256 + tid;
        int row = fi / 24, c4 = fi % 24;
        float4 v = *reinterpret_cast<const float4*>(x + (size_t)(row0+row)*240 + 64 + c4*4);
        int c = c4*4;
        xbuf[((c  )%3)*2560 + row*40 + (c  )/3] = (short)f2bf(v.x);
        xbuf[((c+1)%3)*2560 + row*40 + (c+1)/3] = (short)f2bf(v.y);
        xbuf[((c+2)%3)*2560 + row*40 + (c+2)/3] = (short)f2bf(v.z);
        xbuf[((c+3)%3)*2560 + row*40 + (c+3)/3] = (short)f2bf(v.w);
    }
    __syncthreads();

    // ---------------- phase B: x1 GEMMs (K=32) ----------------
    f32x4 y1[3][2], p5[3][2], p4[3], q4[3];
    {
        const int rl = wv*16 + rr;
        #pragma unroll
        for (int i = 0; i < 3; ++i) {
            short8v a = *reinterpret_cast<const short8v*>(&xbuf[i*2560 + rl*40 + kq*8]);
            #pragma unroll
            for (int nt = 0; nt < 4; ++nt) {
                f32x4 t1 = MFMA16(a, LDW(11264 + nt*512), zf, 0,0,0);
                f32x4 t2 = MFMA16(a, LDW(13312 + nt*512), zf, 0,0,0);
                y0[nt] += C3 * (t1 * t2);
            }
            #pragma unroll
            for (int nt = 0; nt < 2; ++nt) {
                f32x4 t2b = MFMA16(a, LDW(15360 + nt*512), zf, 0,0,0);
                y1[i][nt] = C1c * (t1w[nt] * t2b);
                p5[i][nt] = MFMA16(a, LDW(16384 + nt*512), zf, 0,0,0);
            }
            p4[i] = MFMA16(a, LDW(17408), zf, 0,0,0);
            q4[i] = MFMA16(a, LDW(17920), zf, 0,0,0);
        }
    }
    f32x4 y2[5];
    {
        f32x4 p0=p4[0], p1=p4[1], p2=p4[2], q0=q4[0], q1=q4[1], q2=q4[2];
        y2[0] = (A4*S10) * (p0*q2 + p2*q0);
        y2[1] = (A4*S10) * (p0*q1 + p1*q0);
        y2[2] = (A4*T215) * (p1*q1) - (A4*S30) * (p0*q0 + p2*q2);
        y2[3] = (A4*S10) * (p1*q2 + p2*q1);
        y2[4] = (A4*S10) * (p2*q2 - p0*q0);
    }
    __syncthreads();

    // stage x2d (de-interleaved per component j): xbuf[j*1536 + row*24 + u]
    #pragma unroll
    for (int it = 0; it < 5; ++it) {            // 1280 float4 = 64 rows x 20
        int fi = it*256 + tid;
        int row = fi / 20, c4 = fi % 20;
        float4 v = *reinterpret_cast<const float4*>(x + (size_t)(row0+row)*240 + 160 + c4*4);
        int c = c4*4;
        xbuf[((c  )%5)*1536 + row*24 + (c  )/5] = (short)f2bf(v.x);
        xbuf[((c+1)%5)*1536 + row*24 + (c+1)/5] = (short)f2bf(v.y);
        xbuf[((c+2)%5)*1536 + row*24 + (c+2)/5] = (short)f2bf(v.z);
        xbuf[((c+3)%5)*1536 + row*24 + (c+3)/5] = (short)f2bf(v.w);
    }
    __syncthreads();

    // ---------------- phase C: x2 GEMMs (K=16, half-frags) ----------------
    f32x4 p7[5], q7[5];
    {
        const int rl = wv*16 + rr;
        #pragma unroll
        for (int j = 0; j < 5; ++j) {
            short8v a = z8;
            if (l < 32) a = *reinterpret_cast<const short8v*>(&xbuf[j*1536 + rl*24 + kq*8]);
            #pragma unroll
            for (int nt = 0; nt < 4; ++nt) {
                f32x4 t1 = MFMA16(a, LDWH(18432 + nt*256), zf, 0,0,0);
                f32x4 t2 = MFMA16(a, LDWH(19456 + nt*256), zf, 0,0,0);
                y0[nt] += C6 * (t1 * t2);
            }
            {
                f32x4 t2c = MFMA16(a, LDWH(20992), zf, 0,0,0);
                y2[j] += C2c * (Cw * t2c);
            }
            #pragma unroll
            for (int nt = 0; nt < 2; ++nt) {
                f32x4 q5 = MFMA16(a, LDWH(20480 + nt*256), zf, 0,0,0);
                if (j == 0) { y1[0][nt] += A5S10 * (p5[2][nt]*q5); y1[2][nt] += A5S10 * (p5[0][nt]*q5); }
                if (j == 1) { y1[0][nt] += A5S10 * (p5[1][nt]*q5); y1[1][nt] += A5S10 * (p5[0][nt]*q5); }
                if (j == 2) { y1[0][nt] -= A5S30 * (p5[0][nt]*q5); y1[1][nt] += A5T   * (p5[1][nt]*q5);
                              y1[2][nt] -= A5S30 * (p5[2][nt]*q5); }
                if (j == 3) { y1[1][nt] += A5S10 * (p5[2][nt]*q5); y1[2][nt] += A5S10 * (p5[1][nt]*q5); }
                if (j == 4) { y1[0][nt] -= A5S10 * (p5[0][nt]*q5); y1[2][nt] += A5S10 * (p5[2][nt]*q5); }
            }
            p7[j] = MFMA16(a, LDWH(21248), zf, 0,0,0);
            q7[j] = MFMA16(a, LDWH(21504), zf, 0,0,0);
        }
    }
    {
        f32x4 p0=p7[0], p1=p7[1], p2=p7[2], p3=p7[3], p4v=p7[4];
        f32x4 q0=q7[0], q1=q7[1], q2=q7[2], q3=q7[3], q4v=q7[4];
        y2[0] += A7*( -D35*(p0*q2 + p2*q0) + E70*(p1*q3 + p3*q1) );
        y2[1] += A7*(  E70*(p0*q3 + p3*q0 - p4v*q1 - p1*q4v) + F70*(p1*q2 + p2*q1) );
        y2[2] += A7*(  D35*(p2*q2 - p0*q0 - p4v*q4v) + F70*(p1*q1 + p3*q3) );
        y2[3] += A7*(  E70*(p0*q1 + p1*q0 + p4v*q3 + p3*q4v) + F70*(p3*q2 + p2*q3) );
        y2[4] += A7*( -D35*(p4v*q2 + p2*q4v) + E70*(p3*q3 - p1*q1) );
    }

    // ---------------- epilogue: D layout col=l&15, row=(l>>4)*4+reg ----------------
    const int rbase = row0 + wv*16 + kq*4;
    #pragma unroll
    for (int jj = 0; jj < 4; ++jj) {
        float* po = out + (size_t)(rbase + jj) * 240;
        #pragma unroll
        for (int nt = 0; nt < 4; ++nt) po[nt*16 + rr] = y0[nt][jj];
        #pragma unroll
        for (int i = 0; i < 3; ++i) {
            po[64 + (rr     )*3 + i] = y1[i][0][jj];
            po[64 + (16 + rr)*3 + i] = y1[i][1][jj];
        }
        #pragma unroll
        for (int k = 0; k < 5; ++k) po[160 + rr*5 + k] = y2[k][jj];
    }
#undef LDW
#undef LDWH
}

extern "C" void kernel_launch(void* const* d_in, const int* in_sizes, int n_in,
                              void* d_out, int out_size, void* d_ws, size_t ws_size,
                              hipStream_t stream)
{
    const float* x = (const float*)d_in[0];
    const float* w[17];
    for (int i = 1; i <= 16; ++i) w[i] = (const float*)d_in[i];
    unsigned short* wsp = (unsigned short*)d_ws;
    float* outp = (float*)d_out;

    // slot order: W10 W20 W11 W12 W13 W23 W21 W15 W14 W24 W16 W26 W25 W22 W17 W27
    hipLaunchKernelGGL(wprep_kernel, dim3(85), dim3(256), 0, stream,
                       w[1], w[2], w[3], w[5], w[7], w[8], w[4], w[11],
                       w[9], w[10], w[13], w[14], w[12], w[6], w[15], w[16],
                       wsp);
    hipLaunchKernelGGL(stp_mfma, dim3(NROWS / RPB), dim3(TPB), 0, stream,
                       x, wsp, outp);
}